// Round 8
// baseline (1708.368 us; speedup 1.0000x reference)
//
#include <hip/hip_runtime.h>
#include <cstdint>
#include <cstddef>

#define M_DIM 4096
#define N_DIM 8192
#define K_DIM 4096

typedef __attribute__((ext_vector_type(4))) int int4v;

// ---------------------------------------------------------------------------
// Pack into MFMA-fragment order (int32 -> int8). R3/R8-verified, identical.
// p = 16-row panel, s = 64-byte kstep, lane l: chunk(p,s) is 1024 B where
// lane l holds row 16p+(l&15), k-bytes s*64 + (l>>4)*16 .. +16.
// ---------------------------------------------------------------------------
__global__ void __launch_bounds__(256) pack_frag(const int* __restrict__ a,
                                                 const int* __restrict__ b,
                                                 unsigned char* __restrict__ pa,
                                                 unsigned char* __restrict__ pb) {
    size_t t = (size_t)blockIdx.x * 256 + threadIdx.x;
    const size_t NA = (size_t)(M_DIM / 16) * (K_DIM / 64) * 64;
    const int* __restrict__ src;
    unsigned char* __restrict__ dst;
    if (t < NA) {
        src = a; dst = pa;
    } else {
        src = b; dst = pb; t -= NA;
    }
    const int l = (int)(t & 63);
    const int s = (int)((t >> 6) & 63);
    const int p = (int)(t >> 12);
    const int* g = src + ((size_t)(16 * p + (l & 15))) * K_DIM + s * 64 + (l >> 4) * 16;
    const int4v* g4 = (const int4v*)g;
    int4v o;
#pragma unroll
    for (int q = 0; q < 4; ++q) {
        int4v v = g4[q];
        o[q] = (v[0] & 0xff) | ((v[1] & 0xff) << 8) | ((v[2] & 0xff) << 16) | (v[3] << 24);
    }
    ((int4v*)dst)[t] = o;
}

// ---------------------------------------------------------------------------
// GEMM: block 256(M) x 256(N), 512 thr = 8 waves (2M x 4N), wave tile
// 128x64, acc[8][4] = 128 AGPR, mfma_i32_16x16x64_i8, BK=64.
// R3/R5/R6 accounting: reg-pipelining cuts per-iter overhead (449 -> 308
// cyc) but must be amortized over a BIG per-iter MFMA cluster at >=2
// waves/SIMD (R5's 288 regs -> 1 wave/SIMD was the killer). This geometry:
//   * frags: A single-buffered (8x4=32 VGPR) + B double-buffered
//     (2x4x4=32 VGPR) -> ~120 VGPR + 128 AGPR = ~248 <= 256 -> 2 waves/SIMD.
//   * per iter per SIMD: 64 MFMA = 1306 cyc >> LDS 768/CU -> MFMA-bound.
//   * 3 x 32 KB LDS buffers; DMA issued 3 tiles ahead into o_cur (tile T's
//     buffer, whose reads completed last iter and are lgkm-drained before
//     the previous barrier); boundary = lgkmcnt(0) + counted vmcnt(4)
//     (tile T+2 completes, T+3 stays in flight) + ONE s_barrier per iter.
//   * iter T: issue DMA(T+3); read B(T+1) -> other bf set; 32 MFMA from
//     af/bf regs loaded last iter; read A(T+1) -> af (WAR on af pins these
//     AFTER the MFMAs; latency hides under the ~650cy MFMA pipe drain).
//   * no setprio (m190: hurts non-8-phase GEMM; starves staging waves).
// ---------------------------------------------------------------------------
__device__ inline void async_copy16(const unsigned char* g, unsigned char* l) {
    __builtin_amdgcn_global_load_lds(
        (const __attribute__((address_space(1))) void*)g,
        (__attribute__((address_space(3))) void*)l,
        16, 0, 0);
}

#define BAR() __builtin_amdgcn_s_barrier()

__global__ void __launch_bounds__(512, 2) gemm_i8(const unsigned char* __restrict__ Ap,
                                                  const unsigned char* __restrict__ Bp,
                                                  const _Float16* __restrict__ arow,
                                                  const _Float16* __restrict__ acol,
                                                  _Float16* __restrict__ Cout) {
    // buffer b at b*32768: A panels [0,16K), B panels [16K,32K)
    __shared__ __align__(16) unsigned char lds[3 * 32768];

    const int tid  = threadIdx.x;
    const int lane = tid & 63;
    const int wave = tid >> 6;   // 0..7
    const int wr   = wave >> 2;  // 0..1  (M half)
    const int wc   = wave & 3;   // 0..3  (N quarter)
    const int bn   = blockIdx.x; // 0..31 (256 cols)
    const int bm   = blockIdx.y; // 0..15 (256 rows)

    // staging: wave w stages A panels {2w,2w+1} and B panels {2w,2w+1};
    // 4 chunks = 4 KB per wave per K-tile (32 KB per tile per block).
    const unsigned char* aG[2];
    const unsigned char* bG[2];
    int aL[2], bL[2];
#pragma unroll
    for (int r = 0; r < 2; ++r) {
        const int p = 2 * wave + r;
        aG[r] = Ap + (size_t)(bm * 16 + p) * 65536 + lane * 16;
        aL[r] = p * 1024;  // wave-uniform; HW adds lane*16
        bG[r] = Bp + (size_t)(bn * 16 + p) * 65536 + lane * 16;
        bL[r] = 16384 + p * 1024;
    }

    const int a_off = wr * 8192 + lane * 16;          // af[i]: + i*1024, i=0..7
    const int b_off = 16384 + wc * 4096 + lane * 16;  // bf[j]: + j*1024, j=0..3

    int4v acc[8][4];
#pragma unroll
    for (int i = 0; i < 8; ++i)
#pragma unroll
        for (int j = 0; j < 4; ++j) acc[i][j] = (int4v)0;

    const int NT = K_DIM / 64;  // 64

    // prologue: stage tiles 0,1,2 into buffers 0,1,2 (12 loads/wave)
#pragma unroll
    for (int t = 0; t < 3; ++t) {
        const size_t gk = (size_t)t * 1024;
        const int lo = t * 32768;
#pragma unroll
        for (int r = 0; r < 2; ++r) async_copy16(aG[r] + gk, lds + lo + aL[r]);
#pragma unroll
        for (int r = 0; r < 2; ++r) async_copy16(bG[r] + gk, lds + lo + bL[r]);
    }
    asm volatile("s_waitcnt vmcnt(4)" ::: "memory");  // tiles 0,1 resident; 2 in flight
    BAR();

    // preload: af <- tile 0 A, bf0 <- tile 0 B
    int4v af[8], bf0[4], bf1[4];
#pragma unroll
    for (int i = 0; i < 8; ++i) af[i] = *(const int4v*)(lds + a_off + i * 1024);
#pragma unroll
    for (int j = 0; j < 4; ++j) bf0[j] = *(const int4v*)(lds + b_off + j * 1024);
    asm volatile("s_waitcnt lgkmcnt(0)" ::: "memory");  // before DMA(3) hits buf0

    int o_cur = 0, o_nxt = 32768, o_pre = 65536;

#pragma unroll 1
    for (int u = 0; u < NT / 2; ++u) {
        // ========== even iter: T=2u — MFMA(af,bf0); load T+1 -> bf1, af =====
        {
            const int T = 2 * u;
            if (T + 3 < NT) {  // DMA tile T+3 into o_cur (tile T's buffer, free)
                const size_t gk = (size_t)(T + 3) * 1024;
#pragma unroll
                for (int r = 0; r < 2; ++r) async_copy16(aG[r] + gk, lds + o_cur + aL[r]);
#pragma unroll
                for (int r = 0; r < 2; ++r) async_copy16(bG[r] + gk, lds + o_cur + bL[r]);
            }
            const unsigned char* Rb = lds + o_nxt;  // tile T+1 (resident)
#pragma unroll
            for (int j = 0; j < 4; ++j) bf1[j] = *(const int4v*)(Rb + b_off + j * 1024);
#pragma unroll
            for (int i = 0; i < 8; ++i)
#pragma unroll
                for (int j = 0; j < 4; ++j)
                    acc[i][j] = __builtin_amdgcn_mfma_i32_16x16x64_i8(af[i], bf0[j],
                                                                      acc[i][j], 0, 0, 0);
            // A-reads AFTER the MFMA cluster (WAR on af pins the order);
            // latency hides under the MFMA pipe drain.
#pragma unroll
            for (int i = 0; i < 8; ++i) af[i] = *(const int4v*)(Rb + a_off + i * 1024);
            asm volatile("s_waitcnt lgkmcnt(0)" ::: "memory");
            if (T + 3 < NT) {
                asm volatile("s_waitcnt vmcnt(4)" ::: "memory");  // T+2 done, T+3 in flight
            } else {
                asm volatile("s_waitcnt vmcnt(0)" ::: "memory");
            }
            BAR();
            const int t0 = o_cur; o_cur = o_nxt; o_nxt = o_pre; o_pre = t0;
        }
        // ========== odd iter: T=2u+1 — MFMA(af,bf1); load T+1 -> bf0, af ====
        {
            const int T = 2 * u + 1;
            if (T + 3 < NT) {
                const size_t gk = (size_t)(T + 3) * 1024;
#pragma unroll
                for (int r = 0; r < 2; ++r) async_copy16(aG[r] + gk, lds + o_cur + aL[r]);
#pragma unroll
                for (int r = 0; r < 2; ++r) async_copy16(bG[r] + gk, lds + o_cur + bL[r]);
            }
            if (T + 1 < NT) {
                const unsigned char* Rb = lds + o_nxt;
#pragma unroll
                for (int j = 0; j < 4; ++j) bf0[j] = *(const int4v*)(Rb + b_off + j * 1024);
#pragma unroll
                for (int i = 0; i < 8; ++i)
#pragma unroll
                    for (int j = 0; j < 4; ++j)
                        acc[i][j] = __builtin_amdgcn_mfma_i32_16x16x64_i8(af[i], bf1[j],
                                                                          acc[i][j], 0, 0, 0);
#pragma unroll
                for (int i = 0; i < 8; ++i) af[i] = *(const int4v*)(Rb + a_off + i * 1024);
            } else {  // T = NT-1: last tile, no further loads
#pragma unroll
                for (int i = 0; i < 8; ++i)
#pragma unroll
                    for (int j = 0; j < 4; ++j)
                        acc[i][j] = __builtin_amdgcn_mfma_i32_16x16x64_i8(af[i], bf1[j],
                                                                          acc[i][j], 0, 0, 0);
            }
            asm volatile("s_waitcnt lgkmcnt(0)" ::: "memory");
            if (T + 3 < NT) {
                asm volatile("s_waitcnt vmcnt(4)" ::: "memory");
            } else {
                asm volatile("s_waitcnt vmcnt(0)" ::: "memory");
            }
            BAR();
            const int t0 = o_cur; o_cur = o_nxt; o_nxt = o_pre; o_pre = t0;
        }
    }

    // --- epilogue: C/D layout col=lane&15, row=(lane>>4)*4+reg (verified)
    const int gcol0 = bn * 256 + wc * 64 + (lane & 15);
    float ac4[4];
#pragma unroll
    for (int j = 0; j < 4; ++j) ac4[j] = (float)acol[gcol0 + j * 16];

    const size_t grow0 = (size_t)bm * 256 + wr * 128 + (lane >> 4) * 4;
#pragma unroll
    for (int i = 0; i < 8; ++i) {
#pragma unroll
        for (int r = 0; r < 4; ++r) {
            const size_t row = grow0 + i * 16 + r;
            const float ar = (float)arow[row];
            _Float16* outp = Cout + row * (size_t)N_DIM + gcol0;
#pragma unroll
            for (int j = 0; j < 4; ++j) {
                float v = (float)acc[i][j][r] * ar * ac4[j];
                outp[j * 16] = (_Float16)v;
            }
        }
    }
}

// ---------------------------------------------------------------------------
extern "C" void kernel_launch(void* const* d_in, const int* in_sizes, int n_in,
                              void* d_out, int out_size, void* d_ws, size_t ws_size,
                              hipStream_t stream) {
    const int* a = (const int*)d_in[0];             // [M,K] int32 (int8 values)
    const int* b = (const int*)d_in[1];             // [N,K] int32 (int8 values)
    const _Float16* ar = (const _Float16*)d_in[2];  // [M] fp16
    const _Float16* ac = (const _Float16*)d_in[3];  // [N] fp16
    _Float16* out = (_Float16*)d_out;               // [M,N] fp16

    unsigned char* pa = (unsigned char*)d_ws;        // 16 MB
    unsigned char* pb = pa + (size_t)M_DIM * K_DIM;  // 32 MB

    const size_t total_frag = (size_t)(M_DIM / 16 + N_DIM / 16) * (K_DIM / 64) * 64;
    pack_frag<<<(int)(total_frag / 256), 256, 0, stream>>>(a, b, pa, pb);

    dim3 grid(N_DIM / 256, M_DIM / 256);
    gemm_i8<<<grid, 512, 0, stream>>>(pa, pb, ar, ac, out);
}

// Round 9
// 366.990 us; speedup vs baseline: 4.6551x; 4.6551x over previous
//
#include <hip/hip_runtime.h>
#include <cstdint>
#include <cstddef>

#define M_DIM 4096
#define N_DIM 8192
#define K_DIM 4096

typedef __attribute__((ext_vector_type(4))) int int4v;

// ---------------------------------------------------------------------------
// Pack into MFMA-fragment order (int32 -> int8). R3/R8-verified, identical.
// p = 16-row panel, s = 64-byte kstep, lane l: chunk(p,s) is 1024 B where
// lane l holds row 16p+(l&15), k-bytes s*64 + (l>>4)*16 .. +16.
// ---------------------------------------------------------------------------
__global__ void __launch_bounds__(256) pack_frag(const int* __restrict__ a,
                                                 const int* __restrict__ b,
                                                 unsigned char* __restrict__ pa,
                                                 unsigned char* __restrict__ pb) {
    size_t t = (size_t)blockIdx.x * 256 + threadIdx.x;
    const size_t NA = (size_t)(M_DIM / 16) * (K_DIM / 64) * 64;
    const int* __restrict__ src;
    unsigned char* __restrict__ dst;
    if (t < NA) {
        src = a; dst = pa;
    } else {
        src = b; dst = pb; t -= NA;
    }
    const int l = (int)(t & 63);
    const int s = (int)((t >> 6) & 63);
    const int p = (int)(t >> 12);
    const int* g = src + ((size_t)(16 * p + (l & 15))) * K_DIM + s * 64 + (l >> 4) * 16;
    const int4v* g4 = (const int4v*)g;
    int4v o;
#pragma unroll
    for (int q = 0; q < 4; ++q) {
        int4v v = g4[q];
        o[q] = (v[0] & 0xff) | ((v[1] & 0xff) << 8) | ((v[2] & 0xff) << 16) | (v[3] << 24);
    }
    ((int4v*)dst)[t] = o;
}

// ---------------------------------------------------------------------------
// GEMM: block 256(M) x 256(N), 512 thr = 8 waves (2M x 4N), wave tile
// 128x64, acc[8][4] = 128 AGPR, mfma_i32_16x16x64_i8, BK=64.
// R8 POST-MORTEM: CSV VGPR_Count excludes AGPRs (R5 cross-check). R8 hit
// the 2-waves/SIMD cap (256 unified = 128 AGPR acc + 128 arch-VGPR) and
// needed ~156 arch-VGPRs -> ~28 spilled -> 6.3 GB scratch traffic, 11x
// slower. Fix: cut persistent register state to what R2 proved fits:
//   * A-fragments TRANSIENT: af[8] read at the top of iter T from tile T's
//     buffer, consumed by this iter's MFMAs. Compiler's fine-grained
//     lgkmcnt interleaves the 8 ds_reads with the 32-MFMA cluster
//     (MFMA group i waits only on af[i]) -> ~1 read latency exposed.
//   * Only B double-buffered (bf0/bf1 = 32 VGPR persistent): MFMA(T) uses
//     bf loaded at iter T-1; iter T loads B(T+1) into the other set.
//   * Persistent-at-barrier: acc(AGPR) + 16 VGPR bf + ~12 addressing
//     -> arch-VGPR ~100-115 < 128 cap. No spill.
//   * 4 LDS buffers (4 x 32 KB = 128 KB, 1 block/CU): DMA(T+3) -> buf
//     (T+3)&3, never equal to read buffers T&3 / (T+1)&3. Reuse window:
//     buf (T+3)&3's last readers (tile T-1, iters T-2/T-1) are
//     lgkm-complete before their consuming MFMAs, hence before
//     barrier(T-1), which precedes this issue. No explicit lgkmcnt(0).
//   * vmcnt ledger (4 loads/wave/tile, lookahead 3): at boundary(T)
//     outstanding {T+2,T+3}=8 -> vmcnt(4) completes T+2 (needed by iter
//     T+1's reads). Tail T>=61: no issues, drain vmcnt(0). One s_barrier
//     per iter. Counted wait never 0 in steady state.
// ---------------------------------------------------------------------------
__device__ inline void async_copy16(const unsigned char* g, unsigned char* l) {
    __builtin_amdgcn_global_load_lds(
        (const __attribute__((address_space(1))) void*)g,
        (__attribute__((address_space(3))) void*)l,
        16, 0, 0);
}

#define BAR() __builtin_amdgcn_s_barrier()

__global__ void __launch_bounds__(512, 2) gemm_i8(const unsigned char* __restrict__ Ap,
                                                  const unsigned char* __restrict__ Bp,
                                                  const _Float16* __restrict__ arow,
                                                  const _Float16* __restrict__ acol,
                                                  _Float16* __restrict__ Cout) {
    // buffer for tile t at (t&3)*32768: A panels [0,16K), B panels [16K,32K)
    __shared__ __align__(16) unsigned char lds[4 * 32768];

    const int tid  = threadIdx.x;
    const int lane = tid & 63;
    const int wave = tid >> 6;   // 0..7
    const int wr   = wave >> 2;  // 0..1  (M half)
    const int wc   = wave & 3;   // 0..3  (N quarter)
    const int bn   = blockIdx.x; // 0..31 (256 cols)
    const int bm   = blockIdx.y; // 0..15 (256 rows)

    // staging: wave w stages A panels {2w,2w+1} and B panels {2w,2w+1};
    // 4 chunks = 4 KB per wave per K-tile (32 KB per tile per block).
    // Running pointers advanced +1024 per issued tile (no per-iter mul).
    const unsigned char* aP0 = Ap + (size_t)(bm * 16 + 2 * wave) * 65536 + lane * 16;
    const unsigned char* aP1 = aP0 + 65536;
    const unsigned char* bP0 = Bp + (size_t)(bn * 16 + 2 * wave) * 65536 + lane * 16;
    const unsigned char* bP1 = bP0 + 65536;
    const int aL0 = 2 * wave * 1024, aL1 = aL0 + 1024;
    const int bL0 = 16384 + 2 * wave * 1024, bL1 = bL0 + 1024;

#define STAGE(lo)                                  \
    do {                                           \
        async_copy16(aP0, lds + (lo) + aL0);       \
        async_copy16(aP1, lds + (lo) + aL1);       \
        async_copy16(bP0, lds + (lo) + bL0);       \
        async_copy16(bP1, lds + (lo) + bL1);       \
        aP0 += 1024; aP1 += 1024;                  \
        bP0 += 1024; bP1 += 1024;                  \
    } while (0)

    const int a_off = wr * 8192 + lane * 16;          // af[i]: + i*1024, i=0..7
    const int b_off = 16384 + wc * 4096 + lane * 16;  // bf[j]: + j*1024, j=0..3

    int4v acc[8][4];
#pragma unroll
    for (int i = 0; i < 8; ++i)
#pragma unroll
        for (int j = 0; j < 4; ++j) acc[i][j] = (int4v)0;

    const int NT = K_DIM / 64;  // 64

    // prologue: stage tiles 0,1,2 into buffers 0,1,2
    STAGE(0);
    STAGE(32768);
    STAGE(65536);
    asm volatile("s_waitcnt vmcnt(4)" ::: "memory");  // tiles 0,1 resident; 2 in flight
    BAR();

    // preload bf0 <- tile 0 B (consumed by iter 0's MFMAs)
    int4v bf0[4], bf1[4];
#pragma unroll
    for (int j = 0; j < 4; ++j) bf0[j] = *(const int4v*)(lds + b_off + j * 1024);

#pragma unroll 1
    for (int u = 0; u < NT / 2; ++u) {
        // ========== even iter: T=2u — af(T) transient; MFMA x bf0; B(T+1)->bf1
        {
            const int T = 2 * u;
            if (T + 3 < NT) STAGE(((T + 3) & 3) * 32768);
            const unsigned char* Ac = lds + (T & 3) * 32768;
            const unsigned char* Bn = lds + ((T + 1) & 3) * 32768;  // T+1<NT (T even <=62)
            int4v af[8];
#pragma unroll
            for (int i = 0; i < 8; ++i) af[i] = *(const int4v*)(Ac + a_off + i * 1024);
#pragma unroll
            for (int j = 0; j < 4; ++j) bf1[j] = *(const int4v*)(Bn + b_off + j * 1024);
#pragma unroll
            for (int i = 0; i < 8; ++i)
#pragma unroll
                for (int j = 0; j < 4; ++j)
                    acc[i][j] = __builtin_amdgcn_mfma_i32_16x16x64_i8(af[i], bf0[j],
                                                                      acc[i][j], 0, 0, 0);
            if (T + 3 < NT) {
                asm volatile("s_waitcnt vmcnt(4)" ::: "memory");  // T+2 done, T+3 in flight
            } else {
                asm volatile("s_waitcnt vmcnt(0)" ::: "memory");
            }
            BAR();
        }
        // ========== odd iter: T=2u+1 — af(T) transient; MFMA x bf1; B(T+1)->bf0
        {
            const int T = 2 * u + 1;
            if (T + 3 < NT) STAGE(((T + 3) & 3) * 32768);
            const unsigned char* Ac = lds + (T & 3) * 32768;
            int4v af[8];
#pragma unroll
            for (int i = 0; i < 8; ++i) af[i] = *(const int4v*)(Ac + a_off + i * 1024);
            if (T + 1 < NT) {
                const unsigned char* Bn = lds + ((T + 1) & 3) * 32768;
#pragma unroll
                for (int j = 0; j < 4; ++j) bf0[j] = *(const int4v*)(Bn + b_off + j * 1024);
            }
#pragma unroll
            for (int i = 0; i < 8; ++i)
#pragma unroll
                for (int j = 0; j < 4; ++j)
                    acc[i][j] = __builtin_amdgcn_mfma_i32_16x16x64_i8(af[i], bf1[j],
                                                                      acc[i][j], 0, 0, 0);
            if (T + 3 < NT) {
                asm volatile("s_waitcnt vmcnt(4)" ::: "memory");
            } else {
                asm volatile("s_waitcnt vmcnt(0)" ::: "memory");
            }
            BAR();
        }
    }
#undef STAGE

    // --- epilogue: C/D layout col=lane&15, row=(lane>>4)*4+reg (verified)
    const int gcol0 = bn * 256 + wc * 64 + (lane & 15);
    float ac4[4];
#pragma unroll
    for (int j = 0; j < 4; ++j) ac4[j] = (float)acol[gcol0 + j * 16];

    const size_t grow0 = (size_t)bm * 256 + wr * 128 + (lane >> 4) * 4;
#pragma unroll
    for (int i = 0; i < 8; ++i) {
#pragma unroll
        for (int r = 0; r < 4; ++r) {
            const size_t row = grow0 + i * 16 + r;
            const float ar = (float)arow[row];
            _Float16* outp = Cout + row * (size_t)N_DIM + gcol0;
#pragma unroll
            for (int j = 0; j < 4; ++j) {
                float v = (float)acc[i][j][r] * ar * ac4[j];
                outp[j * 16] = (_Float16)v;
            }
        }
    }
}

// ---------------------------------------------------------------------------
extern "C" void kernel_launch(void* const* d_in, const int* in_sizes, int n_in,
                              void* d_out, int out_size, void* d_ws, size_t ws_size,
                              hipStream_t stream) {
    const int* a = (const int*)d_in[0];             // [M,K] int32 (int8 values)
    const int* b = (const int*)d_in[1];             // [N,K] int32 (int8 values)
    const _Float16* ar = (const _Float16*)d_in[2];  // [M] fp16
    const _Float16* ac = (const _Float16*)d_in[3];  // [N] fp16
    _Float16* out = (_Float16*)d_out;               // [M,N] fp16

    unsigned char* pa = (unsigned char*)d_ws;        // 16 MB
    unsigned char* pb = pa + (size_t)M_DIM * K_DIM;  // 32 MB

    const size_t total_frag = (size_t)(M_DIM / 16 + N_DIM / 16) * (K_DIM / 64) * 64;
    pack_frag<<<(int)(total_frag / 256), 256, 0, stream>>>(a, b, pa, pb);

    dim3 grid(N_DIM / 256, M_DIM / 256);
    gemm_i8<<<grid, 512, 0, stream>>>(pa, pb, ar, ac, out);
}